// Round 1
// baseline (4184.538 us; speedup 1.0000x reference)
//
#include <hip/hip_runtime.h>

typedef unsigned int uint;

constexpr int D_IN   = 768;
constexpr int D_SAE  = 16384;   // 2^14
constexpr int BATCH  = 4096;
constexpr int TOTAL_K = 64 * 4096;          // 262144
constexpr size_t NPRE = (size_t)BATCH * D_SAE;  // 67,108,864

// ---------------- workspace layout (bytes) ----------------
constexpr size_t CTRL_OFF   = 0;                       // 16 uints
// ctrl[0]=nnz ctrl[1]=bA ctrl[2]=C_A ctrl[3]=bB ctrl[4]=C_B
// ctrl[5]=nCandC ctrl[6]=tau_bits ctrl[7]=need_ties
constexpr size_t HISTA_OFF  = 64;                      // 4096 uints
constexpr size_t HISTB_OFF  = HISTA_OFF + 4096 * 4;    // 4096 uints
constexpr size_t ROWCNT_OFF = HISTB_OFF + 4096 * 4;    // BATCH uints
constexpr size_t ZERO_BYTES = ROWCNT_OFF + BATCH * 4;  // memset region end
constexpr size_t ROWOFF_OFF = ZERO_BYTES;              // BATCH+1 uints (pad 64)
constexpr size_t CURSOR_OFF = ROWOFF_OFF + (BATCH + 64) * 4;
constexpr size_t TIEKEEP_OFF = CURSOR_OFF + BATCH * 4; // 1024 uints
constexpr int    CANDC_CAP  = 8192;
constexpr size_t CANDC_OFF  = TIEKEEP_OFF + 1024 * 4;  // uint2 * CANDC_CAP
constexpr size_t COMPACT_OFF = CANDC_OFF + CANDC_CAP * 8;      // uint2 * (TOTAL_K+1024)
constexpr size_t GROUPED_OFF = COMPACT_OFF + (TOTAL_K + 1024) * 8;

// ---------------- encoder GEMM: pre = relu((x - b_dec) @ W_enc + b_enc) ----------------
__global__ __launch_bounds__(256) void enc_gemm(
    const float* __restrict__ x, const float* __restrict__ W,
    const float* __restrict__ benc, const float* __restrict__ bdec,
    float* __restrict__ pre)
{
  __shared__ float xs[32][132];
  __shared__ float wsh[32][132];
  const int tid = threadIdx.x;
  const int ty = tid >> 4, tx = tid & 15;
  const int m0 = blockIdx.y * 128;
  const int n0 = blockIdx.x * 128;

  float acc[8][8];
#pragma unroll
  for (int i = 0; i < 8; ++i)
#pragma unroll
    for (int j = 0; j < 8; ++j) acc[i][j] = 0.f;

  for (int k0 = 0; k0 < D_IN; k0 += 32) {
    // x tile: 128 rows x 32 k  (subtract b_dec on the way in)
#pragma unroll
    for (int r = 0; r < 4; ++r) {
      int chunk = tid + 256 * r;
      int row = chunk >> 3, c4 = (chunk & 7) * 4;
      float4 v  = *(const float4*)(x + (size_t)(m0 + row) * D_IN + k0 + c4);
      float4 bd = *(const float4*)(bdec + k0 + c4);
      xs[c4 + 0][row] = v.x - bd.x;
      xs[c4 + 1][row] = v.y - bd.y;
      xs[c4 + 2][row] = v.z - bd.z;
      xs[c4 + 3][row] = v.w - bd.w;
    }
    // W tile: 32 k x 128 cols
#pragma unroll
    for (int r = 0; r < 4; ++r) {
      int chunk = tid + 256 * r;
      int k = chunk >> 5, c4 = (chunk & 31) * 4;
      float4 v = *(const float4*)(W + (size_t)(k0 + k) * D_SAE + n0 + c4);
      *(float4*)&wsh[k][c4] = v;
    }
    __syncthreads();
#pragma unroll 4
    for (int k = 0; k < 32; ++k) {
      float a[8], b[8];
      *(float4*)&a[0] = *(const float4*)&xs[k][ty * 4];
      *(float4*)&a[4] = *(const float4*)&xs[k][64 + ty * 4];
      *(float4*)&b[0] = *(const float4*)&wsh[k][tx * 4];
      *(float4*)&b[4] = *(const float4*)&wsh[k][64 + tx * 4];
#pragma unroll
      for (int i = 0; i < 8; ++i)
#pragma unroll
        for (int j = 0; j < 8; ++j)
          acc[i][j] = fmaf(a[i], b[j], acc[i][j]);
    }
    __syncthreads();
  }
  // epilogue: + b_enc, relu, store
#pragma unroll
  for (int i = 0; i < 8; ++i) {
    int row = m0 + ((i < 4) ? (ty * 4 + i) : (64 + ty * 4 + i - 4));
    float* outr = pre + (size_t)row * D_SAE + n0;
#pragma unroll
    for (int jj = 0; jj < 2; ++jj) {
      int cb = (jj == 0) ? (tx * 4) : (64 + tx * 4);
      float4 be = *(const float4*)(benc + n0 + cb);
      float4 o;
      o.x = fmaxf(acc[i][jj * 4 + 0] + be.x, 0.f);
      o.y = fmaxf(acc[i][jj * 4 + 1] + be.y, 0.f);
      o.z = fmaxf(acc[i][jj * 4 + 2] + be.z, 0.f);
      o.w = fmaxf(acc[i][jj * 4 + 3] + be.w, 0.f);
      *(float4*)(outr + cb) = o;
    }
  }
}

// ---------------- pass A: histogram of bits>>20 (4096 bins), skip zeros ----------------
__global__ __launch_bounds__(256) void hist_hi(const uint* __restrict__ pre, uint* __restrict__ histA)
{
  __shared__ uint h[4096];
  for (int i = threadIdx.x; i < 4096; i += 256) h[i] = 0;
  __syncthreads();
  size_t n4 = NPRE / 4;
  size_t stride = (size_t)gridDim.x * 256;
  for (size_t i = (size_t)blockIdx.x * 256 + threadIdx.x; i < n4; i += stride) {
    uint4 v = ((const uint4*)pre)[i];
    if (v.x) atomicAdd(&h[v.x >> 20], 1u);
    if (v.y) atomicAdd(&h[v.y >> 20], 1u);
    if (v.z) atomicAdd(&h[v.z >> 20], 1u);
    if (v.w) atomicAdd(&h[v.w >> 20], 1u);
  }
  __syncthreads();
  for (int i = threadIdx.x; i < 4096; i += 256) if (h[i]) atomicAdd(&histA[i], h[i]);
}

// ---------------- crossing-bin search over a 4096-bin histogram ----------------
// stage 0: hist=histA base=0      -> ctrl[1]=bA ctrl[2]=C_A
// stage 1: hist=histB base=C_A    -> ctrl[3]=bB ctrl[4]=C_B
__global__ __launch_bounds__(256) void select_bin(const uint* __restrict__ hist, uint* ctrl, int stage)
{
  __shared__ uint ssum[256];
  int t = threadIdx.x;
  // thread t covers bins [4096-16*(t+1), 4096-16*t), i.e. t=0 is the TOP 16 bins
  int hi = 4096 - 16 * t;     // exclusive
  uint sum = 0;
  for (int b = hi - 16; b < hi; ++b) sum += hist[b];
  ssum[t] = sum;
  __syncthreads();
  if (t == 0) {
    uint base = (stage == 0) ? 0u : ctrl[2];
    uint need = TOTAL_K;
    uint C = base;
    int tc = 255;
    for (int i = 0; i < 256; ++i) {
      if (C + ssum[i] >= need) { tc = i; break; }
      C += ssum[i];
    }
    int top = 4096 - 16 * tc - 1;
    uint bin = 0;
    for (int b = top; b >= top - 15; --b) {
      uint c = hist[b];
      if (C + c >= need) { bin = (uint)b; break; }
      C += c;
      if (b == top - 15) bin = (uint)b; // fallback (should not happen)
    }
    if (stage == 0) { ctrl[1] = bin; ctrl[2] = C; }
    else            { ctrl[3] = bin; ctrl[4] = C; }
  }
}

// ---------------- pass B: histogram of (bits>>8)&0xFFF for elements in bin bA ----------------
__global__ __launch_bounds__(256) void hist_mid(const uint* __restrict__ pre, const uint* __restrict__ ctrl,
                                                uint* __restrict__ histB)
{
  uint bA = ctrl[1];
  size_t n4 = NPRE / 4;
  size_t stride = (size_t)gridDim.x * 256;
  for (size_t i = (size_t)blockIdx.x * 256 + threadIdx.x; i < n4; i += stride) {
    uint4 v = ((const uint4*)pre)[i];
    if ((v.x >> 20) == bA) atomicAdd(&histB[(v.x >> 8) & 0xFFFu], 1u);
    if ((v.y >> 20) == bA) atomicAdd(&histB[(v.y >> 8) & 0xFFFu], 1u);
    if ((v.z >> 20) == bA) atomicAdd(&histB[(v.z >> 8) & 0xFFFu], 1u);
    if ((v.w >> 20) == bA) atomicAdd(&histB[(v.w >> 8) & 0xFFFu], 1u);
  }
}

// ---------------- pass C: collect (bits, idx) of elements whose top-24 bits match ----------------
__global__ __launch_bounds__(256) void collect_cand(const uint* __restrict__ pre, uint* __restrict__ ctrl,
                                                    uint2* __restrict__ cand)
{
  uint target = (ctrl[1] << 12) | ctrl[3];
  size_t n4 = NPRE / 4;
  size_t stride = (size_t)gridDim.x * 256;
  for (size_t i = (size_t)blockIdx.x * 256 + threadIdx.x; i < n4; i += stride) {
    uint4 v = ((const uint4*)pre)[i];
    uint base = (uint)(i * 4);
    if ((v.x >> 8) == target) { uint p = atomicAdd(&ctrl[5], 1u); if (p < CANDC_CAP) cand[p] = make_uint2(v.x, base + 0); }
    if ((v.y >> 8) == target) { uint p = atomicAdd(&ctrl[5], 1u); if (p < CANDC_CAP) cand[p] = make_uint2(v.y, base + 1); }
    if ((v.z >> 8) == target) { uint p = atomicAdd(&ctrl[5], 1u); if (p < CANDC_CAP) cand[p] = make_uint2(v.z, base + 2); }
    if ((v.w >> 8) == target) { uint p = atomicAdd(&ctrl[5], 1u); if (p < CANDC_CAP) cand[p] = make_uint2(v.w, base + 3); }
  }
}

// ---------------- final: exact tau + stable (smallest-index) tie selection ----------------
__global__ __launch_bounds__(256) void final_select(uint* __restrict__ ctrl, const uint2* __restrict__ cand,
                                                    uint* __restrict__ tiekeep)
{
  __shared__ uint h[256];
  __shared__ uint s_tau, s_need, s_m;
  __shared__ uint s_tie[1024];
  int t = threadIdx.x;
  h[t] = 0;
  if (t == 0) s_m = 0;
  __syncthreads();
  uint nC = min(ctrl[5], (uint)CANDC_CAP);
  uint C_B = ctrl[4];
  uint need = TOTAL_K - C_B;   // >= 1 by construction
  for (uint i = t; i < nC; i += 256) atomicAdd(&h[cand[i].x & 0xFFu], 1u);
  __syncthreads();
  if (t == 0) {
    uint c = 0, v = 0, cgt = 0;
    for (int b = 255; b >= 0; --b) {
      if (c + h[b] >= need) { v = (uint)b; cgt = c; break; }
      c += h[b];
    }
    uint target = (ctrl[1] << 12) | ctrl[3];
    s_tau = (target << 8) | v;
    s_need = need - cgt;       // #ties to keep, >= 1
    ctrl[6] = s_tau;
    ctrl[7] = s_need;
  }
  __syncthreads();
  uint tau = s_tau;
  for (uint i = t; i < nC; i += 256)
    if (cand[i].x == tau) { uint p = atomicAdd(&s_m, 1u); if (p < 1024) s_tie[p] = cand[i].y; }
  __syncthreads();
  uint m = min(s_m, 1024u);
  uint nt = s_need;
  for (uint i = t; i < m; i += 256) {
    uint my = s_tie[i];
    uint rank = 0;
    for (uint j = 0; j < m; ++j) rank += (s_tie[j] < my) ? 1u : 0u;
    if (rank < nt) tiekeep[rank] = my;   // keep the nt smallest flat indices
  }
}

// ---------------- mask: z = (pre > tau) ? pre : 0 ; compact kept entries ----------------
__global__ __launch_bounds__(256) void mask_kernel(uint* __restrict__ z, uint* __restrict__ ctrl,
                                                   uint2* __restrict__ compact, uint* __restrict__ rowcnt)
{
  uint tau = ctrl[6];
  size_t n4 = NPRE / 4;
  size_t stride = (size_t)gridDim.x * 256;
  for (size_t i = (size_t)blockIdx.x * 256 + threadIdx.x; i < n4; i += stride) {
    uint4 v = ((const uint4*)z)[i];
    uint4 o;
    o.x = (v.x > tau) ? v.x : 0u;
    o.y = (v.y > tau) ? v.y : 0u;
    o.z = (v.z > tau) ? v.z : 0u;
    o.w = (v.w > tau) ? v.w : 0u;
    ((uint4*)z)[i] = o;
    uint base = (uint)(i * 4);
    if (v.x > tau) { uint p = atomicAdd(&ctrl[0], 1u); compact[p] = make_uint2(base + 0, v.x); atomicAdd(&rowcnt[(base + 0) >> 14], 1u); }
    if (v.y > tau) { uint p = atomicAdd(&ctrl[0], 1u); compact[p] = make_uint2(base + 1, v.y); atomicAdd(&rowcnt[(base + 1) >> 14], 1u); }
    if (v.z > tau) { uint p = atomicAdd(&ctrl[0], 1u); compact[p] = make_uint2(base + 2, v.z); atomicAdd(&rowcnt[(base + 2) >> 14], 1u); }
    if (v.w > tau) { uint p = atomicAdd(&ctrl[0], 1u); compact[p] = make_uint2(base + 3, v.w); atomicAdd(&rowcnt[(base + 3) >> 14], 1u); }
  }
}

// ---------------- ties: re-insert the kept ==tau elements ----------------
__global__ void tie_fix(uint* __restrict__ ctrl, const uint* __restrict__ tiekeep,
                        float* __restrict__ z, uint2* __restrict__ compact, uint* __restrict__ rowcnt)
{
  uint nt = ctrl[7];
  uint tau = ctrl[6];
  for (uint t = threadIdx.x; t < nt; t += blockDim.x) {
    uint idx = tiekeep[t];
    z[idx] = __uint_as_float(tau);
    uint p = atomicAdd(&ctrl[0], 1u);
    compact[p] = make_uint2(idx, tau);
    atomicAdd(&rowcnt[idx >> 14], 1u);
  }
}

// ---------------- prefix sum over row counts ----------------
__global__ __launch_bounds__(256) void prefix_rows(const uint* __restrict__ rowcnt,
                                                   uint* __restrict__ rowoff, uint* __restrict__ cursor)
{
  __shared__ uint s[256];
  __shared__ uint pref[257];
  int t = threadIdx.x;
  uint loc[16], sum = 0;
#pragma unroll
  for (int r = 0; r < 16; ++r) { loc[r] = rowcnt[t * 16 + r]; sum += loc[r]; }
  s[t] = sum;
  __syncthreads();
  if (t == 0) {
    uint a = 0;
    for (int i = 0; i < 256; ++i) { pref[i] = a; a += s[i]; }
    pref[256] = a;
  }
  __syncthreads();
  uint off = pref[t];
#pragma unroll
  for (int r = 0; r < 16; ++r) {
    rowoff[t * 16 + r] = off;
    cursor[t * 16 + r] = off;
    off += loc[r];
  }
  if (t == 255) rowoff[BATCH] = off;
}

// ---------------- scatter: group compact list by row ----------------
__global__ __launch_bounds__(256) void scatter_rows(const uint* __restrict__ ctrl, const uint2* __restrict__ compact,
                                                    uint* __restrict__ cursor, uint2* __restrict__ grouped)
{
  uint nnz = ctrl[0];
  uint i = blockIdx.x * 256 + threadIdx.x;
  if (i < nnz) {
    uint2 e = compact[i];
    uint row = e.x >> 14;
    uint p = atomicAdd(&cursor[row], 1u);
    grouped[p] = e;
  }
}

// ---------------- sparse decode: x_hat[r,:] = b_dec + sum v * W_dec[j,:] ----------------
__global__ __launch_bounds__(256) void decode_kernel(const uint* __restrict__ rowoff, const uint2* __restrict__ grouped,
                                                     const float* __restrict__ Wdec, const float* __restrict__ bdec,
                                                     float* __restrict__ xhat)
{
  int r = blockIdx.x;
  int t = threadIdx.x;
  uint beg = rowoff[r], end = rowoff[r + 1];
  float a0 = bdec[t], a1 = bdec[t + 256], a2 = bdec[t + 512];
  __shared__ uint2 ch[128];
  for (uint c0 = beg; c0 < end; c0 += 128) {
    uint m = min(128u, end - c0);
    if (t < (int)m) ch[t] = grouped[c0 + t];
    __syncthreads();
    for (uint e = 0; e < m; ++e) {
      uint2 en = ch[e];
      float v = __uint_as_float(en.y);
      uint j = en.x & (D_SAE - 1);
      const float* wr = Wdec + (size_t)j * D_IN;
      a0 = fmaf(v, wr[t], a0);
      a1 = fmaf(v, wr[t + 256], a1);
      a2 = fmaf(v, wr[t + 512], a2);
    }
    __syncthreads();
  }
  float* out = xhat + (size_t)r * D_IN;
  out[t] = a0; out[t + 256] = a1; out[t + 512] = a2;
}

extern "C" void kernel_launch(void* const* d_in, const int* in_sizes, int n_in,
                              void* d_out, int out_size, void* d_ws, size_t ws_size,
                              hipStream_t stream)
{
  const float* x    = (const float*)d_in[0];
  const float* Wenc = (const float*)d_in[1];
  const float* benc = (const float*)d_in[2];
  const float* Wdec = (const float*)d_in[3];
  const float* bdec = (const float*)d_in[4];

  float* xhat = (float*)d_out;                       // [4096, 768]
  float* z    = (float*)d_out + (size_t)BATCH * D_IN; // [4096, 16384]; holds pre, then masked in-place

  char* ws = (char*)d_ws;
  uint*  ctrl    = (uint*)(ws + CTRL_OFF);
  uint*  histA   = (uint*)(ws + HISTA_OFF);
  uint*  histB   = (uint*)(ws + HISTB_OFF);
  uint*  rowcnt  = (uint*)(ws + ROWCNT_OFF);
  uint*  rowoff  = (uint*)(ws + ROWOFF_OFF);
  uint*  cursor  = (uint*)(ws + CURSOR_OFF);
  uint*  tiekeep = (uint*)(ws + TIEKEEP_OFF);
  uint2* cand    = (uint2*)(ws + CANDC_OFF);
  uint2* compact = (uint2*)(ws + COMPACT_OFF);
  uint2* grouped = (uint2*)(ws + GROUPED_OFF);

  hipMemsetAsync(d_ws, 0, ZERO_BYTES, stream);

  dim3 ggrid(D_SAE / 128, BATCH / 128);
  enc_gemm<<<ggrid, 256, 0, stream>>>(x, Wenc, benc, bdec, z);

  hist_hi<<<4096, 256, 0, stream>>>((const uint*)z, histA);
  select_bin<<<1, 256, 0, stream>>>(histA, ctrl, 0);
  hist_mid<<<4096, 256, 0, stream>>>((const uint*)z, ctrl, histB);
  select_bin<<<1, 256, 0, stream>>>(histB, ctrl, 1);
  collect_cand<<<4096, 256, 0, stream>>>((const uint*)z, ctrl, cand);
  final_select<<<1, 256, 0, stream>>>(ctrl, cand, tiekeep);

  mask_kernel<<<4096, 256, 0, stream>>>((uint*)z, ctrl, compact, rowcnt);
  tie_fix<<<1, 64, 0, stream>>>(ctrl, tiekeep, z, compact, rowcnt);
  prefix_rows<<<1, 256, 0, stream>>>(rowcnt, rowoff, cursor);
  scatter_rows<<<TOTAL_K / 256, 256, 0, stream>>>(ctrl, compact, cursor, grouped);
  decode_kernel<<<BATCH, 256, 0, stream>>>(rowoff, grouped, Wdec, bdec, xhat);
}

// Round 2
// 1596.880 us; speedup vs baseline: 2.6204x; 2.6204x over previous
//
#include <hip/hip_runtime.h>

typedef unsigned int uint;

constexpr int D_IN   = 768;
constexpr int D_SAE  = 16384;   // 2^14
constexpr int BATCH  = 4096;
constexpr int TOTAL_K = 64 * 4096;          // 262144
constexpr size_t NPRE = (size_t)BATCH * D_SAE;  // 67,108,864

// ---------------- workspace layout (bytes) ----------------
// ctrl[0]=nnz(compact) ctrl[1]=bA ctrl[2]=C_A ctrl[3]=bB ctrl[4]=C_B
// ctrl[5]=nCand ctrl[6]=tau_bits ctrl[7]=need_ties ctrl[8]=nCand2
constexpr size_t CTRL_OFF   = 0;                       // 16 uints
constexpr size_t HISTA_OFF  = 64;                      // 4096 uints
constexpr size_t HISTB_OFF  = HISTA_OFF + 4096 * 4;    // 4096 uints
constexpr size_t ROWCNT_OFF = HISTB_OFF + 4096 * 4;    // BATCH uints
constexpr size_t ZERO_BYTES = ROWCNT_OFF + BATCH * 4;  // memset region end
constexpr size_t ROWOFF_OFF = ZERO_BYTES;              // BATCH+1 uints (pad)
constexpr size_t CURSOR_OFF = ROWOFF_OFF + (BATCH + 64) * 4;
constexpr size_t TIEKEEP_OFF = CURSOR_OFF + BATCH * 4; // 1024 uints
constexpr size_t CAND2_OFF  = TIEKEEP_OFF + 4096;      // uint2 * 4096
constexpr int    CAND_CAP   = 524288;
// cand is DEAD once collect24 has run; compact/grouped (written by mask/
// scatter, which run after) overlap the same region to bound ws usage.
constexpr size_t CAND_OFF    = CAND2_OFF + 4096 * 8;
constexpr size_t COMPACT_OFF = CAND_OFF;                        // uint2*(TOTAL_K+1024)
constexpr size_t GROUPED_OFF = COMPACT_OFF + (TOTAL_K + 1024) * 8;

// ---------------- encoder GEMM: pre = relu((x - b_dec) @ W_enc + b_enc) ----------------
__global__ __launch_bounds__(256) void enc_gemm(
    const float* __restrict__ x, const float* __restrict__ W,
    const float* __restrict__ benc, const float* __restrict__ bdec,
    float* __restrict__ pre)
{
  __shared__ float xs[32][132];
  __shared__ float wsh[32][132];
  const int tid = threadIdx.x;
  const int ty = tid >> 4, tx = tid & 15;
  const int m0 = blockIdx.y * 128;
  const int n0 = blockIdx.x * 128;

  float acc[8][8];
#pragma unroll
  for (int i = 0; i < 8; ++i)
#pragma unroll
    for (int j = 0; j < 8; ++j) acc[i][j] = 0.f;

  for (int k0 = 0; k0 < D_IN; k0 += 32) {
#pragma unroll
    for (int r = 0; r < 4; ++r) {
      int chunk = tid + 256 * r;
      int row = chunk >> 3, c4 = (chunk & 7) * 4;
      float4 v  = *(const float4*)(x + (size_t)(m0 + row) * D_IN + k0 + c4);
      float4 bd = *(const float4*)(bdec + k0 + c4);
      xs[c4 + 0][row] = v.x - bd.x;
      xs[c4 + 1][row] = v.y - bd.y;
      xs[c4 + 2][row] = v.z - bd.z;
      xs[c4 + 3][row] = v.w - bd.w;
    }
#pragma unroll
    for (int r = 0; r < 4; ++r) {
      int chunk = tid + 256 * r;
      int k = chunk >> 5, c4 = (chunk & 31) * 4;
      float4 v = *(const float4*)(W + (size_t)(k0 + k) * D_SAE + n0 + c4);
      *(float4*)&wsh[k][c4] = v;
    }
    __syncthreads();
#pragma unroll 4
    for (int k = 0; k < 32; ++k) {
      float a[8], b[8];
      *(float4*)&a[0] = *(const float4*)&xs[k][ty * 4];
      *(float4*)&a[4] = *(const float4*)&xs[k][64 + ty * 4];
      *(float4*)&b[0] = *(const float4*)&wsh[k][tx * 4];
      *(float4*)&b[4] = *(const float4*)&wsh[k][64 + tx * 4];
#pragma unroll
      for (int i = 0; i < 8; ++i)
#pragma unroll
        for (int j = 0; j < 8; ++j)
          acc[i][j] = fmaf(a[i], b[j], acc[i][j]);
    }
    __syncthreads();
  }
#pragma unroll
  for (int i = 0; i < 8; ++i) {
    int row = m0 + ((i < 4) ? (ty * 4 + i) : (64 + ty * 4 + i - 4));
    float* outr = pre + (size_t)row * D_SAE + n0;
#pragma unroll
    for (int jj = 0; jj < 2; ++jj) {
      int cb = (jj == 0) ? (tx * 4) : (64 + tx * 4);
      float4 be = *(const float4*)(benc + n0 + cb);
      float4 o;
      o.x = fmaxf(acc[i][jj * 4 + 0] + be.x, 0.f);
      o.y = fmaxf(acc[i][jj * 4 + 1] + be.y, 0.f);
      o.z = fmaxf(acc[i][jj * 4 + 2] + be.z, 0.f);
      o.w = fmaxf(acc[i][jj * 4 + 3] + be.w, 0.f);
      *(float4*)(outr + cb) = o;
    }
  }
}

// ---------------- pass A: histogram of bits>>20 (4096 bins), skip zeros ----------------
__global__ __launch_bounds__(256) void hist_hi(const uint* __restrict__ pre, uint* __restrict__ histA)
{
  __shared__ uint h[4096];
  for (int i = threadIdx.x; i < 4096; i += 256) h[i] = 0;
  __syncthreads();
  size_t n4 = NPRE / 4;
  size_t stride = (size_t)gridDim.x * 256;
  for (size_t i = (size_t)blockIdx.x * 256 + threadIdx.x; i < n4; i += stride) {
    uint4 v = ((const uint4*)pre)[i];
    if (v.x) atomicAdd(&h[v.x >> 20], 1u);
    if (v.y) atomicAdd(&h[v.y >> 20], 1u);
    if (v.z) atomicAdd(&h[v.z >> 20], 1u);
    if (v.w) atomicAdd(&h[v.w >> 20], 1u);
  }
  __syncthreads();
  for (int i = threadIdx.x; i < 4096; i += 256) if (h[i]) atomicAdd(&histA[i], h[i]);
}

// ---------------- crossing-bin search over a 4096-bin histogram ----------------
__global__ __launch_bounds__(256) void select_bin(const uint* __restrict__ hist, uint* ctrl, int stage)
{
  __shared__ uint ssum[256];
  int t = threadIdx.x;
  int hi = 4096 - 16 * t;     // thread t covers the t-th 16-bin chunk from the TOP
  uint sum = 0;
  for (int b = hi - 16; b < hi; ++b) sum += hist[b];
  ssum[t] = sum;
  __syncthreads();
  if (t == 0) {
    uint base = (stage == 0) ? 0u : ctrl[2];
    uint need = TOTAL_K;
    uint C = base;
    int tc = 255;
    for (int i = 0; i < 256; ++i) {
      if (C + ssum[i] >= need) { tc = i; break; }
      C += ssum[i];
    }
    int top = 4096 - 16 * tc - 1;
    uint bin = 0;
    for (int b = top; b >= top - 15; --b) {
      uint c = hist[b];
      if (C + c >= need) { bin = (uint)b; break; }
      C += c;
      if (b == top - 15) bin = (uint)b;
    }
    if (stage == 0) { ctrl[1] = bin; ctrl[2] = C; }
    else            { ctrl[3] = bin; ctrl[4] = C; }
  }
}

// ---------------- collect elements whose top-12 bits == bA (block-aggregated) ----------------
__global__ __launch_bounds__(256) void collect_bin(const uint* __restrict__ pre, uint* __restrict__ ctrl,
                                                   uint2* __restrict__ cand)
{
  __shared__ uint2 ents[1024];
  __shared__ uint scnt, sbase;
  if (threadIdx.x == 0) scnt = 0;
  __syncthreads();
  uint bA = ctrl[1];
  size_t n4 = NPRE / 4;
  size_t stride = (size_t)gridDim.x * 256;
  for (size_t i = (size_t)blockIdx.x * 256 + threadIdx.x; i < n4; i += stride) {
    uint4 v = ((const uint4*)pre)[i];
    uint base = (uint)(i * 4);
#pragma unroll
    for (int c = 0; c < 4; ++c) {
      uint bits = (c == 0) ? v.x : (c == 1) ? v.y : (c == 2) ? v.z : v.w;
      if ((bits >> 20) == bA) {
        uint p = atomicAdd(&scnt, 1u);
        if (p < 1024) ents[p] = make_uint2(bits, base + c);
        else { uint q = atomicAdd(&ctrl[5], 1u); if (q < CAND_CAP) cand[q] = make_uint2(bits, base + c); }
      }
    }
  }
  __syncthreads();
  uint m = min(scnt, 1024u);
  if (threadIdx.x == 0) sbase = atomicAdd(&ctrl[5], m);
  __syncthreads();
  for (uint i = threadIdx.x; i < m; i += 256) {
    uint p = sbase + i;
    if (p < CAND_CAP) cand[p] = ents[i];
  }
}

// ---------------- hist of mid-12 bits over the candidate list ----------------
__global__ __launch_bounds__(256) void hist_mid2(const uint2* __restrict__ cand, const uint* __restrict__ ctrl,
                                                 uint* __restrict__ histB)
{
  __shared__ uint h[4096];
  for (int i = threadIdx.x; i < 4096; i += 256) h[i] = 0;
  __syncthreads();
  uint n = min(ctrl[5], (uint)CAND_CAP);
  uint stride = gridDim.x * 256;
  for (uint i = blockIdx.x * 256 + threadIdx.x; i < n; i += stride)
    atomicAdd(&h[(cand[i].x >> 8) & 0xFFFu], 1u);
  __syncthreads();
  for (int i = threadIdx.x; i < 4096; i += 256) if (h[i]) atomicAdd(&histB[i], h[i]);
}

// ---------------- filter candidates matching 24-bit prefix ----------------
__global__ __launch_bounds__(256) void collect24(const uint2* __restrict__ cand, uint* __restrict__ ctrl,
                                                 uint2* __restrict__ cand2)
{
  uint target = (ctrl[1] << 12) | ctrl[3];
  uint n = min(ctrl[5], (uint)CAND_CAP);
  uint stride = gridDim.x * 256;
  for (uint i = blockIdx.x * 256 + threadIdx.x; i < n; i += stride) {
    uint2 e = cand[i];
    if ((e.x >> 8) == target) {
      uint p = atomicAdd(&ctrl[8], 1u);
      if (p < 4096) cand2[p] = e;
    }
  }
}

// ---------------- final: exact tau + stable (smallest-index) tie selection ----------------
__global__ __launch_bounds__(256) void final_select(uint* __restrict__ ctrl, const uint2* __restrict__ cand2,
                                                    uint* __restrict__ tiekeep)
{
  __shared__ uint h[256];
  __shared__ uint s_tau, s_need, s_m;
  __shared__ uint s_tie[1024];
  int t = threadIdx.x;
  h[t] = 0;
  if (t == 0) s_m = 0;
  __syncthreads();
  uint nC = min(ctrl[8], 4096u);
  uint C_B = ctrl[4];
  uint need = TOTAL_K - C_B;   // >= 1 by construction
  for (uint i = t; i < nC; i += 256) atomicAdd(&h[cand2[i].x & 0xFFu], 1u);
  __syncthreads();
  if (t == 0) {
    uint c = 0, v = 0, cgt = 0;
    for (int b = 255; b >= 0; --b) {
      if (c + h[b] >= need) { v = (uint)b; cgt = c; break; }
      c += h[b];
    }
    uint target = (ctrl[1] << 12) | ctrl[3];
    s_tau = (target << 8) | v;
    s_need = need - cgt;
    ctrl[6] = s_tau;
    ctrl[7] = s_need;
  }
  __syncthreads();
  uint tau = s_tau;
  for (uint i = t; i < nC; i += 256)
    if (cand2[i].x == tau) { uint p = atomicAdd(&s_m, 1u); if (p < 1024) s_tie[p] = cand2[i].y; }
  __syncthreads();
  uint m = min(s_m, 1024u);
  uint nt = s_need;
  for (uint i = t; i < m; i += 256) {
    uint my = s_tie[i];
    uint rank = 0;
    for (uint j = 0; j < m; ++j) rank += (s_tie[j] < my) ? 1u : 0u;
    if (rank < nt) tiekeep[rank] = my;
  }
}

// ---------------- mask: z = (pre > tau) ? pre : 0 ; block-compacted nonzero list ----------------
__global__ __launch_bounds__(256) void mask_kernel(uint* __restrict__ z, uint* __restrict__ ctrl,
                                                   uint2* __restrict__ compact, uint* __restrict__ rowcnt)
{
  __shared__ uint2 ents[1024];
  __shared__ uint scnt, sbase;
  if (threadIdx.x == 0) scnt = 0;
  __syncthreads();
  uint tau = ctrl[6];
  size_t n4 = NPRE / 4;
  size_t stride = (size_t)gridDim.x * 256;
  for (size_t i = (size_t)blockIdx.x * 256 + threadIdx.x; i < n4; i += stride) {
    uint4 v = ((const uint4*)z)[i];
    uint4 o;
    o.x = (v.x > tau) ? v.x : 0u;
    o.y = (v.y > tau) ? v.y : 0u;
    o.z = (v.z > tau) ? v.z : 0u;
    o.w = (v.w > tau) ? v.w : 0u;
    ((uint4*)z)[i] = o;
    uint base = (uint)(i * 4);
#pragma unroll
    for (int c = 0; c < 4; ++c) {
      uint bits = (c == 0) ? v.x : (c == 1) ? v.y : (c == 2) ? v.z : v.w;
      if (bits > tau) {
        atomicAdd(&rowcnt[(base + c) >> 14], 1u);
        uint p = atomicAdd(&scnt, 1u);
        if (p < 1024) ents[p] = make_uint2(base + c, bits);
        else { uint q = atomicAdd(&ctrl[0], 1u); compact[q] = make_uint2(base + c, bits); }
      }
    }
  }
  __syncthreads();
  uint m = min(scnt, 1024u);
  if (threadIdx.x == 0) sbase = atomicAdd(&ctrl[0], m);
  __syncthreads();
  for (uint i = threadIdx.x; i < m; i += 256)
    compact[sbase + i] = ents[i];
}

// ---------------- ties: re-insert the kept ==tau elements ----------------
__global__ void tie_fix(uint* __restrict__ ctrl, const uint* __restrict__ tiekeep,
                        float* __restrict__ z, uint2* __restrict__ compact, uint* __restrict__ rowcnt)
{
  uint nt = ctrl[7];
  uint tau = ctrl[6];
  for (uint t = threadIdx.x; t < nt; t += blockDim.x) {
    uint idx = tiekeep[t];
    z[idx] = __uint_as_float(tau);
    uint p = atomicAdd(&ctrl[0], 1u);
    compact[p] = make_uint2(idx, tau);
    atomicAdd(&rowcnt[idx >> 14], 1u);
  }
}

// ---------------- prefix sum over row counts ----------------
__global__ __launch_bounds__(256) void prefix_rows(const uint* __restrict__ rowcnt,
                                                   uint* __restrict__ rowoff, uint* __restrict__ cursor)
{
  __shared__ uint s[256];
  __shared__ uint pref[257];
  int t = threadIdx.x;
  uint loc[16], sum = 0;
#pragma unroll
  for (int r = 0; r < 16; ++r) { loc[r] = rowcnt[t * 16 + r]; sum += loc[r]; }
  s[t] = sum;
  __syncthreads();
  if (t == 0) {
    uint a = 0;
    for (int i = 0; i < 256; ++i) { pref[i] = a; a += s[i]; }
    pref[256] = a;
  }
  __syncthreads();
  uint off = pref[t];
#pragma unroll
  for (int r = 0; r < 16; ++r) {
    rowoff[t * 16 + r] = off;
    cursor[t * 16 + r] = off;
    off += loc[r];
  }
  if (t == 255) rowoff[BATCH] = off;
}

// ---------------- scatter: group compact list by row ----------------
__global__ __launch_bounds__(256) void scatter_rows(const uint* __restrict__ ctrl, const uint2* __restrict__ compact,
                                                    uint* __restrict__ cursor, uint2* __restrict__ grouped)
{
  uint nnz = ctrl[0];
  uint i = blockIdx.x * 256 + threadIdx.x;
  if (i < nnz) {
    uint2 e = compact[i];
    uint row = e.x >> 14;
    uint p = atomicAdd(&cursor[row], 1u);
    grouped[p] = e;
  }
}

// ---------------- sparse decode ----------------
__global__ __launch_bounds__(256) void decode_kernel(const uint* __restrict__ rowoff, const uint2* __restrict__ grouped,
                                                     const float* __restrict__ Wdec, const float* __restrict__ bdec,
                                                     float* __restrict__ xhat)
{
  int r = blockIdx.x;
  int t = threadIdx.x;
  uint beg = rowoff[r], end = rowoff[r + 1];
  float a0 = bdec[t], a1 = bdec[t + 256], a2 = bdec[t + 512];
  __shared__ uint2 ch[128];
  for (uint c0 = beg; c0 < end; c0 += 128) {
    uint m = min(128u, end - c0);
    if (t < (int)m) ch[t] = grouped[c0 + t];
    __syncthreads();
    for (uint e = 0; e < m; ++e) {
      uint2 en = ch[e];
      float v = __uint_as_float(en.y);
      uint j = en.x & (D_SAE - 1);
      const float* wr = Wdec + (size_t)j * D_IN;
      a0 = fmaf(v, wr[t], a0);
      a1 = fmaf(v, wr[t + 256], a1);
      a2 = fmaf(v, wr[t + 512], a2);
    }
    __syncthreads();
  }
  float* out = xhat + (size_t)r * D_IN;
  out[t] = a0; out[t + 256] = a1; out[t + 512] = a2;
}

extern "C" void kernel_launch(void* const* d_in, const int* in_sizes, int n_in,
                              void* d_out, int out_size, void* d_ws, size_t ws_size,
                              hipStream_t stream)
{
  const float* x    = (const float*)d_in[0];
  const float* Wenc = (const float*)d_in[1];
  const float* benc = (const float*)d_in[2];
  const float* Wdec = (const float*)d_in[3];
  const float* bdec = (const float*)d_in[4];

  float* xhat = (float*)d_out;                        // [4096, 768]
  float* z    = (float*)d_out + (size_t)BATCH * D_IN; // [4096, 16384]

  char* ws = (char*)d_ws;
  uint*  ctrl    = (uint*)(ws + CTRL_OFF);
  uint*  histA   = (uint*)(ws + HISTA_OFF);
  uint*  histB   = (uint*)(ws + HISTB_OFF);
  uint*  rowcnt  = (uint*)(ws + ROWCNT_OFF);
  uint*  rowoff  = (uint*)(ws + ROWOFF_OFF);
  uint*  cursor  = (uint*)(ws + CURSOR_OFF);
  uint*  tiekeep = (uint*)(ws + TIEKEEP_OFF);
  uint2* cand2   = (uint2*)(ws + CAND2_OFF);
  uint2* cand    = (uint2*)(ws + CAND_OFF);
  uint2* compact = (uint2*)(ws + COMPACT_OFF);
  uint2* grouped = (uint2*)(ws + GROUPED_OFF);

  hipMemsetAsync(d_ws, 0, ZERO_BYTES, stream);

  dim3 ggrid(D_SAE / 128, BATCH / 128);
  enc_gemm<<<ggrid, 256, 0, stream>>>(x, Wenc, benc, bdec, z);

  hist_hi<<<2048, 256, 0, stream>>>((const uint*)z, histA);
  select_bin<<<1, 256, 0, stream>>>(histA, ctrl, 0);
  collect_bin<<<1024, 256, 0, stream>>>((const uint*)z, ctrl, cand);
  hist_mid2<<<64, 256, 0, stream>>>(cand, ctrl, histB);
  select_bin<<<1, 256, 0, stream>>>(histB, ctrl, 1);
  collect24<<<64, 256, 0, stream>>>(cand, ctrl, cand2);
  final_select<<<1, 256, 0, stream>>>(ctrl, cand2, tiekeep);

  mask_kernel<<<1024, 256, 0, stream>>>((uint*)z, ctrl, compact, rowcnt);
  tie_fix<<<1, 64, 0, stream>>>(ctrl, tiekeep, z, compact, rowcnt);
  prefix_rows<<<1, 256, 0, stream>>>(rowcnt, rowoff, cursor);
  scatter_rows<<<(TOTAL_K + 1024 + 255) / 256, 256, 0, stream>>>(ctrl, compact, cursor, grouped);
  decode_kernel<<<BATCH, 256, 0, stream>>>(rowoff, grouped, Wdec, bdec, xhat);
}